// Round 9
// baseline (344.668 us; speedup 1.0000x reference)
//
#include <hip/hip_runtime.h>
#include <hip/hip_bf16.h>

typedef __attribute__((ext_vector_type(8))) short bf16x8;
typedef __attribute__((ext_vector_type(8))) unsigned short ushort8;
typedef __attribute__((ext_vector_type(16))) float f32x16;
typedef unsigned int u32;

#define D_DIM 512
#define C_DIM 1024
#define B_DIM 65536

__device__ __forceinline__ unsigned short f2bf(float x) {
  u32 u = __float_as_uint(x);
  u32 r = (u + 0x7fffu + ((u >> 16) & 1u)) >> 16;
  return (unsigned short)r;
}

__device__ __forceinline__ void async16(const void* g, void* l) {
  __builtin_amdgcn_global_load_lds(
      (const __attribute__((address_space(1))) u32*)g,
      (__attribute__((address_space(3))) u32*)l, 16, 0, 0);
}

// sharp(x) = sigmoid(10x-5) + sigmoid(-10x-5)
//          = (E t^2 + 2t + 1) / (E t^2 + (1+E) t + 1),  t = e^(10x-5), E = e^10.
__device__ __forceinline__ float sharpf(float x) {
  float t = __expf(10.f * x - 5.f);
  float u = 22026.4658f * t * t;
  float num = u + 2.f * t + 1.f;
  float den = u + 22027.4658f * t + 1.f;
  return num * __builtin_amdgcn_rcpf(den);
}

// Normalize rows of length 512 (l2, +1e-12 eps) and cast to bf16.
__global__ __launch_bounds__(256) void rownorm_kernel(
    const float* __restrict__ src, unsigned short* __restrict__ dst) {
  int row = blockIdx.x * 4 + (threadIdx.x >> 6);
  int lane = threadIdx.x & 63;
  const float* s = src + (size_t)row * D_DIM + lane * 8;
  float4 v0 = *(const float4*)s;
  float4 v1 = *(const float4*)(s + 4);
  float ss = v0.x * v0.x + v0.y * v0.y + v0.z * v0.z + v0.w * v0.w +
             v1.x * v1.x + v1.y * v1.y + v1.z * v1.z + v1.w * v1.w;
#pragma unroll
  for (int m = 32; m >= 1; m >>= 1) ss += __shfl_xor(ss, m);
  float rinv = rsqrtf(ss + 1e-12f);
  float tv[8] = {v0.x, v0.y, v0.z, v0.w, v1.x, v1.y, v1.z, v1.w};
  ushort8 o;
#pragma unroll
  for (int i = 0; i < 8; ++i) o[i] = f2bf(tv[i] * rinv);
  *(ushort8*)(dst + (size_t)row * D_DIM + lane * 8) = o;
}

// vbT[n][k] = bf16(val[k][n])  (transpose+cast, 32x32 LDS tiles)
__global__ __launch_bounds__(256) void valT_kernel(
    const float* __restrict__ val, unsigned short* __restrict__ vbT) {
  __shared__ float tile[32][33];
  int bx = blockIdx.x & 31;  // n tile
  int by = blockIdx.x >> 5;  // k tile
  int t = threadIdx.x;
  int r = t >> 5, c = t & 31;
#pragma unroll
  for (int i = 0; i < 4; ++i)
    tile[r + i * 8][c] = val[(size_t)(by * 32 + r + i * 8) * C_DIM + bx * 32 + c];
  __syncthreads();
#pragma unroll
  for (int i = 0; i < 4; ++i)
    vbT[(size_t)(bx * 32 + r + i * 8) * C_DIM + by * 32 + c] = f2bf(tile[c][r + i * 8]);
}

// rsum[i] = sum of the 4 per-n-block partials
__global__ __launch_bounds__(256) void rsum_reduce_kernel(
    const float* __restrict__ part, float* __restrict__ rsum) {
  int i = blockIdx.x * 256 + threadIdx.x;
  rsum[i] = (part[i] + part[i + B_DIM]) +
            (part[i + 2 * B_DIM] + part[i + 3 * B_DIM]);
}

// 256x256 GEMM, BK=64, 8 waves (2Mx4N), per-wave 128x64 as 4x2 32x32x16 MFMA
// frags (32x32 ceiling 2495 TF > 16x16's 2075; half the MFMA instrs).
// Round-7 schedule (proven best): head [vmcnt(6)|vmcnt(0 last); BAR]; ph0:
// reads(A band 0 + all B) + stage(T+1,u3) + MFMA; ph1-3: reads(A band p) +
// BAR + stage(T+2,u p-1) + MFMA. One barrier per phase.
// Fragment layout (gfx9 family, C/D verified m74/m101): A lane l holds
// row=l&31, k=(l>>5)*8+e; B same with col=l&31; C/D col=l&31,
// row=(e&3)+8*(e>>2)+4*(l>>5).
template <int K, bool SHARP>
__global__ __launch_bounds__(512, 2) void gemm256_kernel(
    const unsigned short* __restrict__ A, const unsigned short* __restrict__ Bm,
    unsigned short* __restrict__ wout, float* __restrict__ rsum,
    float* __restrict__ fout) {
  __shared__ unsigned short smem[65536];  // 128 KB
  const int NKT = K / 64;
  const int bid = blockIdx.x;
  // XCD-chunked bijective swizzle: nwg=1024, 8 XCDs, 128 per chunk.
  const int wg = (bid & 7) * 128 + (bid >> 3);
  const int m0 = (wg >> 2) * 256;
  const int n0 = (wg & 3) * 256;
  const int t = threadIdx.x;
  const int lane = t & 63;
  const int wv = t >> 6;
  const int wr = wv >> 2;  // 0..1
  const int wc = wv & 3;   // 0..3
  const int lo5 = lane & 31, hi1 = lane >> 5;
  const int swu = (lo5 & 7) << 3;  // read-side XOR swizzle (u16 units)

  const int s_ridx = t >> 3;    // 0..63
  const int s_c = (t & 7) * 8;  // phys col, u16
  auto stage = [&](int T, int k) {
    int r = (s_ridx < 32) ? (k * 32 + s_ridx) : (96 + k * 32 + s_ridx);
    int cl = s_c ^ ((r & 7) << 3);  // inverse-swizzled logical col
    size_t go = (size_t)T * 64 + cl;
    int d = (T & 1) * 32768;
    async16(A + (size_t)(m0 + r) * K + go, &smem[d + r * 64 + s_c]);
    async16(Bm + (size_t)(n0 + r) * K + go, &smem[d + 16384 + r * 64 + s_c]);
  };

  f32x16 acc[4][2];
#pragma unroll
  for (int i = 0; i < 4; ++i)
#pragma unroll
    for (int j = 0; j < 2; ++j)
#pragma unroll
      for (int e = 0; e < 16; ++e) acc[i][j][e] = 0.f;

  // prologue: K-tile 0 fully + 3 units of K-tile 1  (14 loads in flight)
  stage(0, 0); stage(0, 1); stage(0, 2); stage(0, 3);
  stage(1, 0); stage(1, 1); stage(1, 2);

#pragma unroll 1
  for (int T = 0; T < NKT; ++T) {
    if (T == NKT - 1) {
      asm volatile("s_waitcnt vmcnt(0)" ::: "memory");
    } else {
      asm volatile("s_waitcnt vmcnt(6)" ::: "memory");
    }
    __builtin_amdgcn_s_barrier();
    const int d = (T & 1) * 32768;
    bf16x8 bfr[2][4];
    {  // phase 0: A band 0 (4 reads) + all B (8 reads); stage(T+1,3); 8 MFMA
      bf16x8 af[4];
#pragma unroll
      for (int ks = 0; ks < 4; ++ks) {
        int r = wr * 128 + lo5;
        af[ks] = *(const bf16x8*)&smem[d + r * 64 + ((ks * 16 + hi1 * 8) ^ swu)];
      }
#pragma unroll
      for (int ni = 0; ni < 2; ++ni)
#pragma unroll
        for (int ks = 0; ks < 4; ++ks) {
          int r = wc * 64 + ni * 32 + lo5;
          bfr[ni][ks] =
              *(const bf16x8*)&smem[d + 16384 + r * 64 + ((ks * 16 + hi1 * 8) ^ swu)];
        }
      if (T + 1 < NKT) stage(T + 1, 3);
      __builtin_amdgcn_s_setprio(1);
#pragma unroll
      for (int ks = 0; ks < 4; ++ks)
#pragma unroll
        for (int ni = 0; ni < 2; ++ni)
          acc[0][ni] = __builtin_amdgcn_mfma_f32_32x32x16_bf16(
              af[ks], bfr[ni][ks], acc[0][ni], 0, 0, 0);
      __builtin_amdgcn_s_setprio(0);
    }
#pragma unroll
    for (int p = 1; p < 4; ++p) {  // phases 1..3: A band p (4 reads) + 8 MFMA
      bf16x8 af[4];
#pragma unroll
      for (int ks = 0; ks < 4; ++ks) {
        int r = wr * 128 + p * 32 + lo5;
        af[ks] = *(const bf16x8*)&smem[d + r * 64 + ((ks * 16 + hi1 * 8) ^ swu)];
      }
      __builtin_amdgcn_s_barrier();
      if (T + 2 < NKT) stage(T + 2, p - 1);
      __builtin_amdgcn_s_setprio(1);
#pragma unroll
      for (int ks = 0; ks < 4; ++ks)
#pragma unroll
        for (int ni = 0; ni < 2; ++ni)
          acc[p][ni] = __builtin_amdgcn_mfma_f32_32x32x16_bf16(
              af[ks], bfr[ni][ks], acc[p][ni], 0, 0, 0);
      __builtin_amdgcn_s_setprio(0);
    }
  }
  __syncthreads();  // K-loop drained (vmcnt 0 at last head); reuse LDS

  if (SHARP) {
    float rs[4][16];
#pragma unroll
    for (int i = 0; i < 4; ++i)
#pragma unroll
      for (int e = 0; e < 16; ++e) rs[i][e] = 0.f;
    unsigned short* ep = smem;  // 256x256 u16 = 128 KB
#pragma unroll
    for (int mi = 0; mi < 4; ++mi)
#pragma unroll
      for (int ni = 0; ni < 2; ++ni)
#pragma unroll
        for (int e = 0; e < 16; ++e) {
          float s = sharpf(acc[mi][ni][e]);
          rs[mi][e] += s;
          int rl = wr * 128 + mi * 32 + (e & 3) + ((e >> 2) << 3) + (hi1 << 2);
          int cl = (wc * 64 + ni * 32 + lo5) ^ (((rl >> 2) & 1) << 5);
          ep[rl * 256 + cl] = f2bf(s);
        }
    // reduce rs over the 32 lanes sharing each row (butterfly, 5 steps)
#pragma unroll
    for (int mi = 0; mi < 4; ++mi)
#pragma unroll
      for (int e = 0; e < 16; ++e) {
        float v = rs[mi][e];
        v += __shfl_xor(v, 1);
        v += __shfl_xor(v, 2);
        v += __shfl_xor(v, 4);
        v += __shfl_xor(v, 8);
        v += __shfl_xor(v, 16);
        rs[mi][e] = v;
      }
    __syncthreads();
    // coalesced 16B/lane store of the 256x256 tile (un-swizzling on read)
#pragma unroll
    for (int pass = 0; pass < 16; ++pass) {
      int idx = pass * 4096 + t * 8;
      int row = idx >> 8, col = idx & 255;
      int phys = row * 256 + (col ^ (((row >> 2) & 1) << 5));
      *(ushort8*)&wout[(size_t)(m0 + row) * C_DIM + n0 + col] =
          *(const ushort8*)&ep[phys];
    }
    __syncthreads();
    // wc-reduction of row sums via 4 KB of LDS, then plain global store
    float* rbuf = (float*)smem;  // [4][256]
    if (lo5 == 0) {
#pragma unroll
      for (int mi = 0; mi < 4; ++mi)
#pragma unroll
        for (int e = 0; e < 16; ++e)
          rbuf[wc * 256 + wr * 128 + mi * 32 + (e & 3) + ((e >> 2) << 3) +
               (hi1 << 2)] = rs[mi][e];
    }
    __syncthreads();
    if (t < 256) {
      float v = (rbuf[t] + rbuf[256 + t]) + (rbuf[512 + t] + rbuf[768 + t]);
      rsum[(size_t)(wg & 3) * B_DIM + m0 + t] = v;  // rsum = rsum_part here
    }
  } else {
    float rinv[4][16];
#pragma unroll
    for (int mi = 0; mi < 4; ++mi)
#pragma unroll
      for (int g = 0; g < 4; ++g) {
        float4 r4 =
            *(const float4*)&rsum[m0 + wr * 128 + mi * 32 + g * 8 + hi1 * 4];
        rinv[mi][g * 4 + 0] = __builtin_amdgcn_rcpf(r4.x);
        rinv[mi][g * 4 + 1] = __builtin_amdgcn_rcpf(r4.y);
        rinv[mi][g * 4 + 2] = __builtin_amdgcn_rcpf(r4.z);
        rinv[mi][g * 4 + 3] = __builtin_amdgcn_rcpf(r4.w);
      }
#pragma unroll
    for (int mi = 0; mi < 4; ++mi)
#pragma unroll
      for (int ni = 0; ni < 2; ++ni)
#pragma unroll
        for (int e = 0; e < 16; ++e) {
          int rl = wr * 128 + mi * 32 + (e & 3) + ((e >> 2) << 3) + (hi1 << 2);
          fout[(size_t)(m0 + rl) * C_DIM + n0 + wc * 64 + ni * 32 + lo5] =
              acc[mi][ni][e] * rinv[mi][e];
        }
  }
}

extern "C" void kernel_launch(void* const* d_in, const int* in_sizes, int n_in,
                              void* d_out, int out_size, void* d_ws, size_t ws_size,
                              hipStream_t stream) {
  const float* query = (const float*)d_in[0];
  const float* key = (const float*)d_in[1];
  const float* val = (const float*)d_in[2];
  float* out = (float*)d_out;
  const int B = in_sizes[0] / D_DIM;  // 65536

  char* ws = (char*)d_ws;
  unsigned short* kb = (unsigned short*)(ws);                         // 1 MB
  unsigned short* vbT = (unsigned short*)(ws + (1ull << 20));         // 2 MB
  float* rsum_part = (float*)(ws + 3ull * (1ull << 20));              // 1 MB
  unsigned short* qb = (unsigned short*)(ws + 4ull * (1ull << 20));   // 64 MB
  float* rsum = (float*)qb;  // reuses qb region (dead after GEMM1)
  unsigned short* wbf = (unsigned short*)(ws + 68ull * (1ull << 20)); // 128 MB

  rownorm_kernel<<<dim3(B / 4), dim3(256), 0, stream>>>(query, qb);
  rownorm_kernel<<<dim3(C_DIM / 4), dim3(256), 0, stream>>>(key, kb);
  valT_kernel<<<dim3(1024), dim3(256), 0, stream>>>(val, vbT);

  dim3 grid((B / 256) * (C_DIM / 256));  // 1024 blocks
  gemm256_kernel<D_DIM, true><<<grid, dim3(512), 0, stream>>>(qb, kb, wbf, rsum_part, nullptr);
  rsum_reduce_kernel<<<dim3(B / 256), dim3(256), 0, stream>>>(rsum_part, rsum);
  gemm256_kernel<C_DIM, false><<<grid, dim3(512), 0, stream>>>(wbf, vbT, nullptr, rsum, out);
}